// Round 3
// baseline (467.551 us; speedup 1.0000x reference)
//
#include <hip/hip_runtime.h>
#include <hip/hip_bf16.h>

// Problem constants (match reference)
static constexpr int KD  = 64;    // feature dim
static constexpr int KIN = 256;   // concat dim
static constexpr int KH  = 64;    // hidden dim

typedef __attribute__((ext_vector_type(8))) short bf16x8;
typedef __attribute__((ext_vector_type(4))) float f32x4;

__device__ inline unsigned short f2bf(float f) {
  union { float f; unsigned u; } uf; uf.f = f;
  unsigned u = uf.u;
  return (unsigned short)((u + 0x7FFFu + ((u >> 16) & 1u)) >> 16);
}
__device__ inline float bf2f(unsigned short h) {
  union { unsigned u; float f; } x; x.u = ((unsigned)h) << 16; return x.f;
}

__device__ inline bf16x8 pack8(const float* p) {
  float4 lo = *(const float4*)p;
  float4 hi = *(const float4*)(p + 4);
  bf16x8 v;
  v[0] = (short)f2bf(lo.x); v[1] = (short)f2bf(lo.y);
  v[2] = (short)f2bf(lo.z); v[3] = (short)f2bf(lo.w);
  v[4] = (short)f2bf(hi.x); v[5] = (short)f2bf(hi.y);
  v[6] = (short)f2bf(hi.z); v[7] = (short)f2bf(hi.w);
  return v;
}

__device__ inline float sigm(float x) { return 1.0f / (1.0f + __expf(-x)); }
__device__ inline float silu_(float x) { return x * sigm(x); }

// ---------------- K0: weights -> bf16 B^T layout ----------------
__global__ void k_prep(const float* __restrict__ wc1, const float* __restrict__ wg1,
                       const float* __restrict__ wc2, const float* __restrict__ wg2,
                       const float* __restrict__ wo,
                       unsigned short* __restrict__ wc1t, unsigned short* __restrict__ wg1t,
                       unsigned short* __restrict__ wc2t, unsigned short* __restrict__ wg2t,
                       unsigned short* __restrict__ wot) {
  int t = blockIdx.x * blockDim.x + threadIdx.x;
  if (t < KIN * KH) {
    int n = t >> 8, k = t & 255;
    wc1t[t] = f2bf(wc1[k * KH + n]);
    wg1t[t] = f2bf(wg1[k * KH + n]);
  }
  if (t < KH * KD) {
    int n = t >> 6, k = t & 63;
    wc2t[t] = f2bf(wc2[k * KD + n]);
    wg2t[t] = f2bf(wg2[k * KD + n]);
    wot[t]  = f2bf(wo[k * KD + n]);
  }
}

// ---------------- K1: per-angle MLPs; dense bf16 upd write (NO atomics) ---------
__global__ __launch_bounds__(256) void k_angle(
    const float* __restrict__ atom, const float* __restrict__ bond,
    const float* __restrict__ bwt,  const float* __restrict__ ang,
    const int* __restrict__ bgr,
    const unsigned short* __restrict__ wc1t, const unsigned short* __restrict__ wg1t,
    const unsigned short* __restrict__ wc2t, const unsigned short* __restrict__ wg2t,
    const float* __restrict__ bc1, const float* __restrict__ bc2,
    const float* __restrict__ bg1, const float* __restrict__ bg2,
    unsigned short* __restrict__ upd, int ng) {
  constexpr int HS = 72;  // padded LDS row stride (shorts)
  __shared__ unsigned short hbc[4][16 * HS];
  __shared__ unsigned short hbg[4][16 * HS];

  const int wave = threadIdx.x >> 6;
  const int lane = threadIdx.x & 63;
  const int r15 = lane & 15;
  const int ck = lane >> 4;

  const int gbase = blockIdx.x * 64 + wave * 16;
  const int gi = gbase + r15;
  const int g = (gi < ng) ? gi : 0;
  const int ci = bgr[3 * g + 0];
  const int bi = bgr[3 * g + 1];
  const int bj = bgr[3 * g + 2];
  (void)bi;

  // gather A fragments: total[row][k], 8 contiguous k per lane
  bf16x8 a1[8];
  {
    const float* p0 = bond + (long)bi * KD;
    const float* p1 = bond + (long)bj * KD;
    const float* p2 = ang + (long)g * KD;
    const float* p3 = atom + (long)ci * KD;
    const int off8 = ck * 8;
    a1[0] = pack8(p0 + off8);      a1[1] = pack8(p0 + 32 + off8);
    a1[2] = pack8(p1 + off8);      a1[3] = pack8(p1 + 32 + off8);
    a1[4] = pack8(p2 + off8);      a1[5] = pack8(p2 + 32 + off8);
    a1[6] = pack8(p3 + off8);      a1[7] = pack8(p3 + 32 + off8);
  }

  // GEMM1: hidden = total @ W1 + b1  (core and gate)
  f32x4 ac[4], ag[4];
#pragma unroll
  for (int n = 0; n < 4; n++) {
    float b1 = bc1[n * 16 + r15];
    float b2 = bg1[n * 16 + r15];
    ac[n] = (f32x4){b1, b1, b1, b1};
    ag[n] = (f32x4){b2, b2, b2, b2};
  }
#pragma unroll
  for (int s = 0; s < 8; s++) {
    const int koff = s * 32 + ck * 8;
#pragma unroll
    for (int n = 0; n < 4; n++) {
      bf16x8 b_c = *(const bf16x8*)(wc1t + (n * 16 + r15) * KIN + koff);
      bf16x8 b_g = *(const bf16x8*)(wg1t + (n * 16 + r15) * KIN + koff);
      ac[n] = __builtin_amdgcn_mfma_f32_16x16x32_bf16(a1[s], b_c, ac[n], 0, 0, 0);
      ag[n] = __builtin_amdgcn_mfma_f32_16x16x32_bf16(a1[s], b_g, ag[n], 0, 0, 0);
    }
  }

  // silu + stage hidden to LDS as bf16 (transpose for GEMM2 A-fragments)
#pragma unroll
  for (int n = 0; n < 4; n++) {
#pragma unroll
    for (int j = 0; j < 4; j++) {
      const int row = ck * 4 + j;
      const int h = n * 16 + r15;
      hbc[wave][row * HS + h] = f2bf(silu_(ac[n][j]));
      hbg[wave][row * HS + h] = f2bf(silu_(ag[n][j]));
    }
  }
  __syncthreads();

  // GEMM2: out = hidden @ W2 + b2
  bf16x8 a2c[2], a2g[2];
#pragma unroll
  for (int s = 0; s < 2; s++) {
    const int h0 = s * 32 + ck * 8;
    a2c[s] = *(const bf16x8*)(&hbc[wave][r15 * HS + h0]);
    a2g[s] = *(const bf16x8*)(&hbg[wave][r15 * HS + h0]);
  }
  f32x4 oc[4], og[4];
#pragma unroll
  for (int n = 0; n < 4; n++) {
    float b1 = bc2[n * 16 + r15];
    float b2 = bg2[n * 16 + r15];
    oc[n] = (f32x4){b1, b1, b1, b1};
    og[n] = (f32x4){b2, b2, b2, b2};
  }
#pragma unroll
  for (int s = 0; s < 2; s++) {
    const int koff = s * 32 + ck * 8;
#pragma unroll
    for (int n = 0; n < 4; n++) {
      bf16x8 b_c = *(const bf16x8*)(wc2t + (n * 16 + r15) * KH + koff);
      bf16x8 b_g = *(const bf16x8*)(wg2t + (n * 16 + r15) * KH + koff);
      oc[n] = __builtin_amdgcn_mfma_f32_16x16x32_bf16(a2c[s], b_c, oc[n], 0, 0, 0);
      og[n] = __builtin_amdgcn_mfma_f32_16x16x32_bf16(a2g[s], b_g, og[n], 0, 0, 0);
    }
  }

  // epilogue: upd[g] = silu(oc) * sigmoid(og) * bw[bj]   (bw[bi] deferred to k_aggout)
#pragma unroll
  for (int j = 0; j < 4; j++) {
    const int row = ck * 4 + j;
    const int grow = gbase + row;
    const int bja = __shfl(bj, row);
    if (grow < ng) {
      const float* wb = bwt + (long)bja * KD;
      unsigned short* dst = upd + (long)grow * KD;
#pragma unroll
      for (int n = 0; n < 4; n++) {
        const int d = n * 16 + r15;
        dst[d] = f2bf(silu_(oc[n][j]) * sigm(og[n][j]) * wb[d]);
      }
    }
  }
}

// ---------------- CSR build ----------------
__global__ void k_hist(const int* __restrict__ bgr, int* __restrict__ cnt, int ng) {
  int g = blockIdx.x * blockDim.x + threadIdx.x;
  if (g < ng) atomicAdd(&cnt[bgr[3 * g + 1]], 1);
}

// block-level exclusive scan (256/block): part[i] = excl-within-block, bsum[blk] = block total
__global__ __launch_bounds__(256) void k_scan1(const int* __restrict__ cnt,
                                               int* __restrict__ part,
                                               int* __restrict__ bsum, int nb) {
  __shared__ int wsum[4];
  const int tid = threadIdx.x;
  const int i = blockIdx.x * 256 + tid;
  const int lane = tid & 63, w = tid >> 6;
  int orig = (i < nb) ? cnt[i] : 0;
  int v = orig;
#pragma unroll
  for (int d = 1; d < 64; d <<= 1) {
    int t = __shfl_up(v, d);
    if (lane >= d) v += t;
  }
  if (lane == 63) wsum[w] = v;
  __syncthreads();
  int add = 0;
  for (int k = 0; k < w; k++) add += wsum[k];
  v += add;
  if (i < nb) part[i] = v - orig;
  if (tid == 255) bsum[blockIdx.x] = v;
}

// single-block exclusive scan of block sums (nblk <= 1024)
__global__ __launch_bounds__(1024) void k_scan2(const int* __restrict__ bsum,
                                                int* __restrict__ bscan, int nblk) {
  __shared__ int wsum[16];
  const int tid = threadIdx.x;
  const int lane = tid & 63, w = tid >> 6;
  int orig = (tid < nblk) ? bsum[tid] : 0;
  int v = orig;
#pragma unroll
  for (int d = 1; d < 64; d <<= 1) {
    int t = __shfl_up(v, d);
    if (lane >= d) v += t;
  }
  if (lane == 63) wsum[w] = v;
  __syncthreads();
  int add = 0;
  for (int k = 0; k < w; k++) add += wsum[k];
  v += add;
  if (tid < nblk) bscan[tid] = v - orig;
}

__global__ void k_scan3(const int* __restrict__ part, const int* __restrict__ bscan,
                        int* __restrict__ off, int* __restrict__ cur, int nb) {
  int i = blockIdx.x * blockDim.x + threadIdx.x;
  if (i < nb) {
    off[i] = part[i] + bscan[blockIdx.x * blockDim.x >> 8 ? (i >> 8) : (i >> 8)];
    cur[i] = 0;
  }
}

__global__ void k_fill(const int* __restrict__ bgr, const int* __restrict__ off,
                       int* __restrict__ cur, int* __restrict__ ids, int ng) {
  int g = blockIdx.x * blockDim.x + threadIdx.x;
  if (g < ng) {
    int bi = bgr[3 * g + 1];
    int slot = atomicAdd(&cur[bi], 1);
    ids[off[bi] + slot] = g;
  }
}

// ---------------- K3: segment-sum(upd) * bw[b] -> @Wo + bo + bond -> out ---------
__global__ __launch_bounds__(256) void k_aggout(
    const float* __restrict__ bond, const float* __restrict__ bwt,
    const unsigned short* __restrict__ upd,
    const int* __restrict__ off, const int* __restrict__ cnt, const int* __restrict__ ids,
    const unsigned short* __restrict__ wot, const float* __restrict__ bo,
    float* __restrict__ out, int nb) {
  const int wave = threadIdx.x >> 6;
  const int lane = threadIdx.x & 63;
  const int r15 = lane & 15;
  const int ck = lane >> 4;
  const int base = blockIdx.x * 64 + wave * 16;
  const int b = base + r15;
  const bool bvalid = b < nb;
  const int bc = bvalid ? b : 0;
  const int o = off[bc];
  const int c = bvalid ? cnt[bc] : 0;
  const int d0 = ck * 8;

  float acc[16];
#pragma unroll
  for (int e = 0; e < 16; e++) acc[e] = 0.0f;

  int it = 0;
  for (; it + 2 <= c; it += 2) {
    const int a0 = ids[o + it];
    const int a1i = ids[o + it + 1];
    const unsigned short* r0 = upd + (long)a0 * KD;
    const unsigned short* r1 = upd + (long)a1i * KD;
    bf16x8 l0 = *(const bf16x8*)(r0 + d0);
    bf16x8 h0 = *(const bf16x8*)(r0 + 32 + d0);
    bf16x8 l1 = *(const bf16x8*)(r1 + d0);
    bf16x8 h1 = *(const bf16x8*)(r1 + 32 + d0);
#pragma unroll
    for (int e = 0; e < 8; e++) {
      acc[e]     += bf2f((unsigned short)l0[e]) + bf2f((unsigned short)l1[e]);
      acc[8 + e] += bf2f((unsigned short)h0[e]) + bf2f((unsigned short)h1[e]);
    }
  }
  if (it < c) {
    const int a0 = ids[o + it];
    const unsigned short* r0 = upd + (long)a0 * KD;
    bf16x8 l0 = *(const bf16x8*)(r0 + d0);
    bf16x8 h0 = *(const bf16x8*)(r0 + 32 + d0);
#pragma unroll
    for (int e = 0; e < 8; e++) {
      acc[e]     += bf2f((unsigned short)l0[e]);
      acc[8 + e] += bf2f((unsigned short)h0[e]);
    }
  }

  // multiply by bw[b] (the deferred bw[bi] factor)
  {
    const float* w = bwt + (long)bc * KD;
    float4 w0 = *(const float4*)(w + d0);
    float4 w1 = *(const float4*)(w + d0 + 4);
    float4 w2 = *(const float4*)(w + 32 + d0);
    float4 w3 = *(const float4*)(w + 32 + d0 + 4);
    acc[0] *= w0.x;  acc[1] *= w0.y;  acc[2] *= w0.z;  acc[3] *= w0.w;
    acc[4] *= w1.x;  acc[5] *= w1.y;  acc[6] *= w1.z;  acc[7] *= w1.w;
    acc[8] *= w2.x;  acc[9] *= w2.y;  acc[10] *= w2.z; acc[11] *= w2.w;
    acc[12] *= w3.x; acc[13] *= w3.y; acc[14] *= w3.z; acc[15] *= w3.w;
  }

  // pack A fragments: k-slice [ck*8 .. +8) for s=0, [32+ck*8 ..) for s=1
  bf16x8 a[2];
#pragma unroll
  for (int e = 0; e < 8; e++) {
    a[0][e] = (short)f2bf(acc[e]);
    a[1][e] = (short)f2bf(acc[8 + e]);
  }

  f32x4 acc2[4];
#pragma unroll
  for (int n = 0; n < 4; n++) {
    float bv = bo[n * 16 + r15];
    acc2[n] = (f32x4){bv, bv, bv, bv};
  }
#pragma unroll
  for (int s = 0; s < 2; s++) {
    const int koff = s * 32 + ck * 8;
#pragma unroll
    for (int n = 0; n < 4; n++) {
      bf16x8 bf = *(const bf16x8*)(wot + (n * 16 + r15) * KH + koff);
      acc2[n] = __builtin_amdgcn_mfma_f32_16x16x32_bf16(a[s], bf, acc2[n], 0, 0, 0);
    }
  }
#pragma unroll
  for (int n = 0; n < 4; n++) {
#pragma unroll
    for (int j = 0; j < 4; j++) {
      const int orow = base + ck * 4 + j;
      if (orow < nb) {
        const int d = n * 16 + r15;
        out[(long)orow * KD + d] = acc2[n][j] + bond[(long)orow * KD + d];
      }
    }
  }
}

extern "C" void kernel_launch(void* const* d_in, const int* in_sizes, int n_in,
                              void* d_out, int out_size, void* d_ws, size_t ws_size,
                              hipStream_t stream) {
  const float* atom = (const float*)d_in[0];
  const float* bond = (const float*)d_in[1];
  const float* bwt  = (const float*)d_in[2];
  const float* ang  = (const float*)d_in[3];
  const int*   bgr  = (const int*)d_in[4];
  const float* wc1 = (const float*)d_in[5];
  const float* bc1 = (const float*)d_in[6];
  const float* wc2 = (const float*)d_in[7];
  const float* bc2 = (const float*)d_in[8];
  const float* wg1 = (const float*)d_in[9];
  const float* bg1 = (const float*)d_in[10];
  const float* wg2 = (const float*)d_in[11];
  const float* bg2 = (const float*)d_in[12];
  const float* wo  = (const float*)d_in[13];
  const float* bo  = (const float*)d_in[14];

  const int nb = in_sizes[1] / KD;   // bonds (200000)
  const int ng = in_sizes[4] / 3;    // angles (500000)
  float* out = (float*)d_out;

  // workspace layout
  char* p = (char*)d_ws;
  auto alloc = [&](size_t bytes) { char* r = p; p += (bytes + 255) & ~(size_t)255; return r; };
  unsigned short* wc1t = (unsigned short*)alloc((size_t)KIN * KH * 2);
  unsigned short* wg1t = (unsigned short*)alloc((size_t)KIN * KH * 2);
  unsigned short* wc2t = (unsigned short*)alloc((size_t)KH * KD * 2);
  unsigned short* wg2t = (unsigned short*)alloc((size_t)KH * KD * 2);
  unsigned short* wot  = (unsigned short*)alloc((size_t)KH * KD * 2);
  unsigned short* upd  = (unsigned short*)alloc((size_t)ng * KD * 2);
  int* cnt  = (int*)alloc((size_t)nb * 4);
  int* cur  = (int*)alloc((size_t)nb * 4);
  int* offb = (int*)alloc((size_t)nb * 4);
  int* part = (int*)alloc((size_t)nb * 4);
  int* ids  = (int*)alloc((size_t)ng * 4);
  int* bsum  = (int*)alloc(4096);
  int* bscan = (int*)alloc(4096);

  const int nblk = (nb + 255) / 256;   // must be <= 1024 (nb=200000 -> 782)

  hipMemsetAsync(cnt, 0, (size_t)nb * 4, stream);

  k_prep<<<(KIN * KH + 255) / 256, 256, 0, stream>>>(wc1, wg1, wc2, wg2, wo,
                                                     wc1t, wg1t, wc2t, wg2t, wot);

  const int ablocks = (ng + 63) / 64;
  k_angle<<<ablocks, 256, 0, stream>>>(atom, bond, bwt, ang, bgr,
                                       wc1t, wg1t, wc2t, wg2t,
                                       bc1, bc2, bg1, bg2, upd, ng);

  k_hist<<<(ng + 255) / 256, 256, 0, stream>>>(bgr, cnt, ng);
  k_scan1<<<nblk, 256, 0, stream>>>(cnt, part, bsum, nb);
  k_scan2<<<1, 1024, 0, stream>>>(bsum, bscan, nblk);
  k_scan3<<<nblk, 256, 0, stream>>>(part, bscan, offb, cur, nb);
  k_fill<<<(ng + 255) / 256, 256, 0, stream>>>(bgr, offb, cur, ids, ng);

  const int oblocks = (nb + 63) / 64;
  k_aggout<<<oblocks, 256, 0, stream>>>(bond, bwt, upd, offb, cnt, ids,
                                        wot, bo, out, nb);
}